// Round 9
// baseline (144.603 us; speedup 1.0000x reference)
//
#include <hip/hip_runtime.h>

#define C 64
#define T 262144
#define K 8
#define L 256          // output timesteps per block (amplification 1.75x)
#define W 192          // zero-state warm-up steps; worst pole r<=0.93 -> r^192 ~ 9e-7
#define B (T / L)      // 1024 blocks -> 4 blocks/CU (1 wave/SIMD)
#define TT 64          // timesteps per chunk
#define TMAX (T - 16)  // clamp for never-consumed tail prefetches

// One cascade time-step (identical math/order to the validated kernel).
#define STEP(Y1, Y2, U1, U2, XIN)                                            \
  {                                                                          \
    float tkv[K];                                                            \
    tkv[0] = fmaf(b1c[0], U1,                                                \
             fmaf(b2c[0], U2, fmaf(na1[0], Y1[0], na2[0] * Y2[0])));         \
    _Pragma("unroll")                                                        \
    for (int k = 1; k < K; ++k)                                              \
      tkv[k] = fmaf(b1c[k], Y1[k - 1],                                       \
               fmaf(b2c[k], Y2[k - 1],                                       \
               fmaf(na1[k], Y1[k], na2[k] * Y2[k])));                        \
    float o = fmaf(b0c[0], (XIN), tkv[0]);                                   \
    U2 = (XIN);                                                              \
    _Pragma("unroll")                                                        \
    for (int k = 1; k < K; ++k) {                                            \
      float o2 = fmaf(b0c[k], o, tkv[k]);                                    \
      Y2[k - 1] = o;                                                         \
      o = o2;                                                                \
    }                                                                        \
    Y2[K - 1] = o;                                                           \
    lastout = o;                                                             \
  }

// 16 warm-up steps (no output): state update only.
#define GROUP_WARM(XS)                                                       \
  _Pragma("unroll")                                                          \
  for (int jj = 0; jj < 16; jj += 2) {                                       \
    STEP(yA, yB, uA, uB, XS[jj])                                             \
    STEP(yB, yA, uB, uA, XS[jj + 1])                                         \
  }

// 16 emit steps: every 4 steps pack a float4 and store directly to this
// lane's own output row (imm-offset off the per-chunk base). Per-lane rows
// mean each wave store touches 64 distinct 64B lines, but each line is
// fully dirtied by 4 consecutive dwordx4 of the same lane within ~16 steps,
// so L2 write-combines and HBM write traffic stays exact (verify:
// WRITE_SIZE stays 65536 KB). Stores are fire-and-forget.
#define GROUP_OUT(XS, CB)                                                    \
  _Pragma("unroll")                                                          \
  for (int jj = 0; jj < 16; jj += 4) {                                       \
    float4 ov_;                                                              \
    STEP(yA, yB, uA, uB, XS[jj])     ov_.x = lastout;                        \
    STEP(yB, yA, uB, uA, XS[jj + 1]) ov_.y = lastout;                        \
    STEP(yA, yB, uA, uB, XS[jj + 2]) ov_.z = lastout;                        \
    STEP(yB, yA, uB, uA, XS[jj + 3]) ov_.w = lastout;                        \
    *reinterpret_cast<float4*>(&outrow[(CB) + jj]) = ov_;                    \
  }

// 16 sequential floats via 4x global_load_dwordx4 (per-lane row; L1 reuse).
#define LOAD16(DST, PTR)                                                     \
  {                                                                          \
    const float4* p4_ = (const float4*)(PTR);                                \
    float4 q0_ = p4_[0], q1_ = p4_[1], q2_ = p4_[2], q3_ = p4_[3];           \
    DST[0] = q0_.x;  DST[1] = q0_.y;  DST[2] = q0_.z;  DST[3] = q0_.w;       \
    DST[4] = q1_.x;  DST[5] = q1_.y;  DST[6] = q1_.z;  DST[7] = q1_.w;       \
    DST[8] = q2_.x;  DST[9] = q2_.y;  DST[10] = q2_.z; DST[11] = q2_.w;      \
    DST[12] = q3_.x; DST[13] = q3_.y; DST[14] = q3_.z; DST[15] = q3_.w;      \
  }

// Single-wave blocks, warm-up scheme, no barriers, round-4 distance-2 load
// rotation (compiler-managed interleave; round 5 proved forcing a burst +
// sched_barrier regresses). This round's single change: NO LDS AT ALL —
// outputs go straight to global per-lane (deletes 64 ds_write + 64 ds_read
// + 16-iter transpose + lgkm stalls + 524k bank-conflict cycles per
// dispatch, all of which were fully exposed at 1 wave/SIMD).
__global__ __launch_bounds__(64) void sos_kernel(
    const float* __restrict__ x, const float* __restrict__ sos,
    const float* __restrict__ sx, const float* __restrict__ sy,
    float* __restrict__ out) {
  // XCD-chunked swizzle (bijective: 1024 % 8 == 0): warm-up overlap between
  // neighboring time-blocks (192/448 of the window) hits the same XCD's L2.
  const int h = blockIdx.x;
  const int b = (h & 7) * (B / 8) + (h >> 3);
  const int lane = threadIdx.x;  // = channel

  // Wave-uniform coefficients (compiler -> SGPRs). sos row: b0,b1,b2,1,a1,a2
  float b0c[K], b1c[K], b2c[K], na1[K], na2[K];
#pragma unroll
  for (int k = 0; k < K; ++k) {
    b0c[k] = sos[k * 6 + 0];
    b1c[k] = sos[k * 6 + 1];
    b2c[k] = sos[k * 6 + 2];
    na1[k] = -sos[k * 6 + 4];
    na2[k] = -sos[k * 6 + 5];
  }

  const int t_out = b * L;                            // first emitted step
  const int tstart = (t_out >= W) ? (t_out - W) : 0;  // first computed step
  const int nwarm = (t_out - tstart) / TT;            // 0 (b=0) or 3
  const int nch = nwarm + L / TT;                     // 4 (b=0) or 7

  const float* xrow = x + (size_t)lane * T;

  // State init. tstart==0 (b=0): true initial state -> exact.
  // Else: zero y-state, true x history taps.
  float yA[K], yB[K], uA, uB;
  if (tstart == 0) {
    uA = sx[lane * 2 + 0];
    uB = sx[lane * 2 + 1];
#pragma unroll
    for (int k = 0; k < K; ++k) {
      yA[k] = sy[(k * 64 + lane) * 2 + 0];
      yB[k] = sy[(k * 64 + lane) * 2 + 1];
    }
  } else {
    uA = xrow[tstart - 1];
    uB = xrow[tstart - 2];
#pragma unroll
    for (int k = 0; k < K; ++k) { yA[k] = 0.f; yB[k] = 0.f; }
  }

  // Prologue: groups 0,1 of chunk 0 (one exposed load latency per block).
  float xA[16], xB[16], xC[16], xD[16];
  LOAD16(xA, xrow + tstart)
  LOAD16(xB, xrow + tstart + 16)

  float lastout = 0.f;

  // Warm-up chunks (b>0 only): state update, no stores, no OOB risk
  // (tc+95 <= t_out + 47 < T always).
  for (int ch = 0; ch < nwarm; ++ch) {
    const int tc = tstart + ch * TT;
    LOAD16(xC, xrow + tc + 32)
    GROUP_WARM(xA)
    LOAD16(xD, xrow + tc + 48)
    GROUP_WARM(xB)
    LOAD16(xA, xrow + tc + 64)
    GROUP_WARM(xC)
    LOAD16(xB, xrow + tc + 80)
    GROUP_WARM(xD)
  }

  // Emit chunks: identical rotation, direct float4 stores every 4 steps.
  for (int ch = nwarm; ch < nch; ++ch) {
    const int tc = tstart + ch * TT;
    float* outrow = out + (size_t)lane * T + tc;
    LOAD16(xC, xrow + tc + 32)
    GROUP_OUT(xA, 0)
    LOAD16(xD, xrow + tc + 48)
    GROUP_OUT(xB, 16)
    { int tl = tc + 64;  if (tl > TMAX) tl = TMAX;  // next chunk g0
      LOAD16(xA, xrow + tl) }
    GROUP_OUT(xC, 32)
    { int tl = tc + 80;  if (tl > TMAX) tl = TMAX;  // next chunk g1
      LOAD16(xB, xrow + tl) }
    GROUP_OUT(xD, 48)
  }
  (void)lastout;
}

extern "C" void kernel_launch(void* const* d_in, const int* in_sizes, int n_in,
                              void* d_out, int out_size, void* d_ws,
                              size_t ws_size, hipStream_t stream) {
  const float* x = (const float*)d_in[0];    // [C, T]
  const float* sos = (const float*)d_in[1];  // [K, 6]
  const float* sx = (const float*)d_in[2];   // [K, C, 2]
  const float* sy = (const float*)d_in[3];   // [K, C, 2]
  float* out = (float*)d_out;                // [C, T]
  (void)d_ws;

  sos_kernel<<<B, 64, 0, stream>>>(x, sos, sx, sy, out);
}

// Round 10
// 134.891 us; speedup vs baseline: 1.0720x; 1.0720x over previous
//
#include <hip/hip_runtime.h>

#define C 64
#define T 262144
#define K 8
#define KH 4           // sections per wave (wave0: 0-3, wave1: 4-7)
#define L 256          // output timesteps per block (amplification 1.75x)
#define W 192          // zero-state warm-up steps; worst pole r<=0.93 -> r^192 ~ 9e-7
#define B (T / L)      // 1024 blocks x 2 waves -> 8 waves/CU = 2 waves/SIMD
#define TT 64          // timesteps per chunk/phase
#define STRIDE 65      // LDS row stride words; (lane+j)%32 -> 2-way max (free)
#define TMAX (T - 16)  // clamp for never-consumed tail prefetches

// One HALF-cascade time-step (4 sections; same per-section math/order as the
// validated 8-section STEP — wave1's U1/U2 taps carry exactly what Y1[3]/Y2[3]
// carried in the fused version, so outputs are bit-identical).
#define STEP4(Y1, Y2, U1, U2, XIN)                                           \
  {                                                                          \
    float tkv[KH];                                                           \
    tkv[0] = fmaf(b1c[0], U1,                                                \
             fmaf(b2c[0], U2, fmaf(na1[0], Y1[0], na2[0] * Y2[0])));         \
    _Pragma("unroll")                                                        \
    for (int k = 1; k < KH; ++k)                                             \
      tkv[k] = fmaf(b1c[k], Y1[k - 1],                                       \
               fmaf(b2c[k], Y2[k - 1],                                       \
               fmaf(na1[k], Y1[k], na2[k] * Y2[k])));                        \
    float o = fmaf(b0c[0], (XIN), tkv[0]);                                   \
    U2 = (XIN);                                                              \
    _Pragma("unroll")                                                        \
    for (int k = 1; k < KH; ++k) {                                           \
      float o2 = fmaf(b0c[k], o, tkv[k]);                                    \
      Y2[k - 1] = o;                                                         \
      o = o2;                                                                \
    }                                                                        \
    Y2[KH - 1] = o;                                                          \
    lastout = o;                                                             \
  }

// Wave0: 16 steps from register group XS, section-3 output -> handoff row.
#define GROUP_W0(XS, ROW, CB)                                                \
  _Pragma("unroll")                                                          \
  for (int jj = 0; jj < 16; jj += 2) {                                       \
    STEP4(yA, yB, uA, uB, XS[jj])                                            \
    (ROW)[(CB) + jj] = lastout;                                              \
    STEP4(yB, yA, uB, uA, XS[jj + 1])                                        \
    (ROW)[(CB) + jj + 1] = lastout;                                          \
  }

// 16 sequential floats via 4x global_load_dwordx4 (per-lane row; L1 reuse).
#define LOAD16(DST, PTR)                                                     \
  {                                                                          \
    const float4* p4_ = (const float4*)(PTR);                                \
    float4 q0_ = p4_[0], q1_ = p4_[1], q2_ = p4_[2], q3_ = p4_[3];           \
    DST[0] = q0_.x;  DST[1] = q0_.y;  DST[2] = q0_.z;  DST[3] = q0_.w;       \
    DST[4] = q1_.x;  DST[5] = q1_.y;  DST[6] = q1_.z;  DST[7] = q1_.w;       \
    DST[8] = q2_.x;  DST[9] = q2_.y;  DST[10] = q2_.z; DST[11] = q2_.w;      \
    DST[12] = q3_.x; DST[13] = q3_.y; DST[14] = q3_.z; DST[15] = q3_.w;      \
  }

// 2-wave cascade split with 1-chunk software pipeline:
//   phase p: wave0 computes chunk p (sections 0-3) from x-registers into
//            hbuf[p&1]; wave1 computes chunk p-1 (sections 4-7) from
//            hbuf[(p-1)&1] in-place, then transposed coalesced stage-out.
// Rationale (rounds 2/4/5/9): at 1 wave/SIMD the compiler either sinks the
// prefetch (r2/r9, VGPR 68/36 proved it) or a forced schedule loses (r5);
// stalls are structural. A second co-resident wave per SIMD hides them.
// All values bit-identical to the validated single-wave kernel.
__global__ __launch_bounds__(128) void sos_kernel(
    const float* __restrict__ x, const float* __restrict__ sos,
    const float* __restrict__ sx, const float* __restrict__ sy,
    float* __restrict__ out) {
  __shared__ float hbuf[2][64 * STRIDE];  // 33.3 KB -> 4 blocks/CU

  // XCD-chunked swizzle (bijective: 1024 % 8 == 0).
  const int h = blockIdx.x;
  const int b = (h & 7) * (B / 8) + (h >> 3);
  const int wid = threadIdx.x >> 6;   // 0: sections 0-3, 1: sections 4-7
  const int lane = threadIdx.x & 63;  // = channel

  // Per-wave coefficients (wave-uniform). sos row: b0,b1,b2,1,a1,a2
  float b0c[KH], b1c[KH], b2c[KH], na1[KH], na2[KH];
#pragma unroll
  for (int k = 0; k < KH; ++k) {
    const int kg = wid * KH + k;
    b0c[k] = sos[kg * 6 + 0];
    b1c[k] = sos[kg * 6 + 1];
    b2c[k] = sos[kg * 6 + 2];
    na1[k] = -sos[kg * 6 + 4];
    na2[k] = -sos[kg * 6 + 5];
  }

  const int t_out = b * L;                            // first emitted step
  const int tstart = (t_out >= W) ? (t_out - W) : 0;  // first computed step
  const int nwarm = (t_out - tstart) / TT;            // 0 (b=0) or 3
  const int nch = nwarm + L / TT;                     // 4 (b=0) or 7

  const float* xrow = x + (size_t)lane * T;

  // State init. tstart==0 (b=0): true initial state (all-zero arrays in this
  // problem; sx[k] == section-k input history == section-(k-1) output history).
  // Else: zero y-state; wave0 gets true x taps, wave1's section-3-output taps
  // are 0 (identical to the fused kernel's Y1[3]=Y2[3]=0 warm-up init).
  float yA[KH], yB[KH], uA, uB;
  if (tstart == 0) {
    uA = sx[(wid * 256 + lane) * 2 + 0];   // sx[4*wid][lane][0]
    uB = sx[(wid * 256 + lane) * 2 + 1];
#pragma unroll
    for (int k = 0; k < KH; ++k) {
      const int kg = wid * KH + k;
      yA[k] = sy[(kg * 64 + lane) * 2 + 0];
      yB[k] = sy[(kg * 64 + lane) * 2 + 1];
    }
  } else {
    if (wid == 0) {
      uA = xrow[tstart - 1];
      uB = xrow[tstart - 2];
    } else {
      uA = 0.f;
      uB = 0.f;
    }
#pragma unroll
    for (int k = 0; k < KH; ++k) { yA[k] = 0.f; yB[k] = 0.f; }
  }

  // Wave0 prologue: groups 0,1 of chunk 0 (round-4 distance-2 rotation).
  float xA[16], xB[16], xC[16], xD[16];
  if (wid == 0) {
    LOAD16(xA, xrow + tstart)
    LOAD16(xB, xrow + tstart + 16)
  }

  float lastout = 0.f;
  for (int p = 0; p <= nch; ++p) {
    if (wid == 0) {
      if (p < nch) {
        const int tc = tstart + p * TT;
        float* myrow = &hbuf[p & 1][lane * STRIDE];
        LOAD16(xC, xrow + tc + 32)
        GROUP_W0(xA, myrow, 0)
        LOAD16(xD, xrow + tc + 48)
        GROUP_W0(xB, myrow, 16)
        { int tl = tc + 64;  if (tl > TMAX) tl = TMAX;  // next chunk g0
          LOAD16(xA, xrow + tl) }
        GROUP_W0(xC, myrow, 32)
        { int tl = tc + 80;  if (tl > TMAX) tl = TMAX;  // next chunk g1
          LOAD16(xB, xrow + tl) }
        GROUP_W0(xD, myrow, 48)
      }
    } else {
      const int q = p - 1;
      if (q >= 0) {
        const int tq = tstart + q * TT;
        float* myrow = &hbuf[q & 1][lane * STRIDE];
        // Round-4 software pipeline: LDS reads stay >=8 ahead of the
        // in-place lastout writes. Single wave: ds ordering via lgkmcnt.
        float xg0[8], xg1[8];
#pragma unroll
        for (int j = 0; j < 8; ++j) xg0[j] = myrow[j];
        for (int gg = 0; gg < 4; ++gg) {
          const int tb = gg * 16;
#pragma unroll
          for (int j = 0; j < 8; ++j) xg1[j] = myrow[tb + 8 + j];
#pragma unroll
          for (int j = 0; j < 8; j += 2) {
            STEP4(yA, yB, uA, uB, xg0[j])
            myrow[tb + j] = lastout;
            STEP4(yB, yA, uB, uA, xg0[j + 1])
            myrow[tb + j + 1] = lastout;
          }
          if (gg + 1 < 4) {
#pragma unroll
            for (int j = 0; j < 8; ++j) xg0[j] = myrow[tb + 16 + j];
          }
#pragma unroll
          for (int j = 0; j < 8; j += 2) {
            STEP4(yA, yB, uA, uB, xg1[j])
            myrow[tb + 8 + j] = lastout;
            STEP4(yB, yA, uB, uA, xg1[j + 1])
            myrow[tb + 8 + j + 1] = lastout;
          }
        }
        if (q >= nwarm) {
          // Transposed coalesced stage-out (validated r2-r4): lane covers
          // row (4*it + lane/16), cols 4*(lane%16)..+3. Cross-lane reads
          // within this single wave -> hardware-ordered DS, no barrier.
          const float* lbuf = hbuf[q & 1];
          const int rr = lane >> 4;
          const int cc = (lane & 15) * 4;
#pragma unroll
          for (int it = 0; it < 16; ++it) {
            const int r = it * 4 + rr;
            float4 v;
            v.x = lbuf[r * STRIDE + cc + 0];
            v.y = lbuf[r * STRIDE + cc + 1];
            v.z = lbuf[r * STRIDE + cc + 2];
            v.w = lbuf[r * STRIDE + cc + 3];
            *reinterpret_cast<float4*>(&out[(size_t)r * T + tq + cc]) = v;
          }
        }
      }
    }
    __syncthreads();  // phase handoff: wave0's chunk p visible to wave1
  }
  (void)lastout;
}

extern "C" void kernel_launch(void* const* d_in, const int* in_sizes, int n_in,
                              void* d_out, int out_size, void* d_ws,
                              size_t ws_size, hipStream_t stream) {
  const float* x = (const float*)d_in[0];    // [C, T]
  const float* sos = (const float*)d_in[1];  // [K, 6]
  const float* sx = (const float*)d_in[2];   // [K, C, 2]
  const float* sy = (const float*)d_in[3];   // [K, C, 2]
  float* out = (float*)d_out;                // [C, T]
  (void)d_ws;

  sos_kernel<<<B, 128, 0, stream>>>(x, sos, sx, sy, out);
}